// Round 24
// baseline (79.980 us; speedup 1.0000x reference)
//
#include <hip/hip_runtime.h>
#include <hip/hip_bf16.h>

#define HEADS 8
#define DIM_HEAD 32
#define GROUPS 8
#define CCH 256            // channels
#define NTOK 4096          // d*h*w = 16^3
#define EPS 1e-5f
#define GN_SPLIT 32
#define JS 4               // attention j-split

typedef _Float16 half8 __attribute__((ext_vector_type(8)));
typedef _Float16 half4 __attribute__((ext_vector_type(4)));
typedef __fp16   fp16x2 __attribute__((ext_vector_type(2)));   // cvt_pkrtz return type
typedef float f32x4 __attribute__((ext_vector_type(4)));
typedef float f32x16 __attribute__((ext_vector_type(16)));

// -------------------- 1. GroupNorm partial stats --------------------
__global__ void gn_stats_partial(const float* __restrict__ x, float* __restrict__ part) {
    const int g  = blockIdx.y;
    const int sp = blockIdx.x;
    const int M = (CCH / GROUPS) * NTOK;        // 131072 contiguous floats per group
    const int chunk = M / GN_SPLIT;             // 4096
    const float4* p = (const float4*)(x + (size_t)g * M + (size_t)sp * chunk);
    float s = 0.f, ss = 0.f;
    for (int i = threadIdx.x; i < chunk / 4; i += blockDim.x) {
        float4 v = p[i];
        s  += v.x + v.y + v.z + v.w;
        ss += v.x*v.x + v.y*v.y + v.z*v.z + v.w*v.w;
    }
    #pragma unroll
    for (int off = 32; off; off >>= 1) {
        s  += __shfl_down(s,  off);
        ss += __shfl_down(ss, off);
    }
    __shared__ float sh0[8], sh1[8];
    const int wave = threadIdx.x >> 6, lane = threadIdx.x & 63;
    if (lane == 0) { sh0[wave] = s; sh1[wave] = ss; }
    __syncthreads();
    if (threadIdx.x == 0) {
        float S = 0.f, SS = 0.f;
        const int nw = blockDim.x >> 6;
        for (int w = 0; w < nw; ++w) { S += sh0[w]; SS += sh1[w]; }
        part[(g * GN_SPLIT + sp) * 2]     = S;
        part[(g * GN_SPLIT + sp) * 2 + 1] = SS;
    }
}

// -------------------- 2. Fold GN into QKV weights + w_out fp16 + x transpose ----
__global__ __launch_bounds__(256)
void fold_qkv(const float* __restrict__ w, const float* __restrict__ b,
              const float* __restrict__ gamma, const float* __restrict__ beta,
              const float* __restrict__ part, const float* __restrict__ w_out,
              const float* __restrict__ x,
              _Float16* __restrict__ w2h, float* __restrict__ b2,
              _Float16* __restrict__ wouth, _Float16* __restrict__ xT) {
    const int o = blockIdx.x;
    const int c = threadIdx.x;          // 0..255
    if (o >= 4 * CCH) {                 // ---- transpose tile ----
        const int t  = o - 4 * CCH;     // 0..255
        const int jb = (t & 63) * 64;
        const int cb = (t >> 6) * 64;
        __shared__ float tile[64][65];
        const int tj = threadIdx.x & 63, tc = threadIdx.x >> 6;
        #pragma unroll
        for (int cc = 0; cc < 64; cc += 4)
            tile[cc + tc][tj] = x[(size_t)(cb + cc + tc) * NTOK + jb + tj];
        __syncthreads();
        const int wc = threadIdx.x & 63, wj = threadIdx.x >> 6;
        #pragma unroll
        for (int jj = 0; jj < 64; jj += 4)
            xT[(size_t)(jb + jj + wj) * CCH + cb + wc] = (_Float16)tile[wc][jj + wj];
        return;
    }
    if (o >= 3 * CCH) {                 // ---- w_out convert ----
        const int oo = o - 3 * CCH;
        wouth[(size_t)oo * CCH + c] = (_Float16)w_out[(size_t)oo * CCH + c];
        return;
    }
    __shared__ float smean[GROUPS], srstd[GROUPS];
    if (c < GROUPS) {
        float s = 0.f, ss = 0.f;
        #pragma unroll
        for (int i = 0; i < GN_SPLIT; ++i) {
            s  += part[(c * GN_SPLIT + i) * 2];
            ss += part[(c * GN_SPLIT + i) * 2 + 1];
        }
        const float M = (float)((CCH / GROUPS) * NTOK);
        const float mean = s / M;
        const float var  = ss / M - mean * mean;
        smean[c] = mean;
        srstd[c] = rsqrtf(var + EPS);
    }
    __syncthreads();
    const int g = c >> 5;
    const float sc = gamma[c] * srstd[g];
    const float sh = beta[c] - smean[g] * sc;
    const float wv = w[(size_t)o * CCH + c];
    w2h[(size_t)o * CCH + c] = (_Float16)(wv * sc);
    float t = wv * sh;
    #pragma unroll
    for (int off = 32; off; off >>= 1) t += __shfl_down(t, off);
    __shared__ float shred[4];
    const int wave = threadIdx.x >> 6, lane = threadIdx.x & 63;
    if (lane == 0) shred[wave] = t;
    __syncthreads();
    if (threadIdx.x == 0)
        b2[o] = b[o] + shred[0] + shred[1] + shred[2] + shred[3];
}

// -------------------- 3. QKV GEMM via MFMA, 32 outputs/wave --------------------
__global__ __launch_bounds__(256)
void qkv_mfma(const _Float16* __restrict__ w2h, const float* __restrict__ b2,
              const _Float16* __restrict__ xT,
              _Float16* __restrict__ q_h, _Float16* __restrict__ k_h,
              _Float16* __restrict__ vT_h) {
    const int tid = threadIdx.x, w = tid >> 6, lane = tid & 63;
    const int la = lane & 15, lg = lane >> 4;
    const int jb = blockIdx.x * 64 + w * 16;   // wave's 16 tokens
    const int ob = blockIdx.y * 32;            // 32 output rows (32-aligned: same part/h)
    const int part = ob >> 8;
    f32x4 acc0 = {0.f, 0.f, 0.f, 0.f};
    f32x4 acc1 = {0.f, 0.f, 0.f, 0.f};
    if (part < 2) {
        // A = xT token rows (D row = j), B = w2h o-rows (D col = o)
        const _Float16* arow  = xT  + (size_t)(jb + la) * CCH;
        const _Float16* brow0 = w2h + (size_t)(ob + la) * CCH;
        const _Float16* brow1 = w2h + (size_t)(ob + 16 + la) * CCH;
        #pragma unroll
        for (int kk = 0; kk < CCH; kk += 32) {
            const half8 a  = *(const half8*)(arow  + kk + lg * 8);
            const half8 b0 = *(const half8*)(brow0 + kk + lg * 8);
            const half8 b1 = *(const half8*)(brow1 + kk + lg * 8);
            acc0 = __builtin_amdgcn_mfma_f32_16x16x32_f16(a, b0, acc0, 0, 0, 0);
            acc1 = __builtin_amdgcn_mfma_f32_16x16x32_f16(a, b1, acc1, 0, 0, 0);
        }
        const int h = (ob & 255) >> 5;
        const float bias0 = b2[ob + la];
        const float bias1 = b2[ob + 16 + la];
        _Float16* dst = (part == 0) ? q_h : k_h;
        const float scl = (part == 0) ? 0.17677669529663687f : 1.0f;  // 32^-0.5
        #pragma unroll
        for (int r = 0; r < 4; ++r) {
            const int j = jb + lg * 4 + r;
            _Float16* base = dst + ((size_t)h * NTOK + j) * DIM_HEAD;
            base[la]      = (_Float16)((acc0[r] + bias0) * scl);
            base[16 + la] = (_Float16)((acc1[r] + bias1) * scl);
        }
    } else {
        // A = w2h o-rows (D row = o=d), B = xT token rows (D col = j)
        const _Float16* arow0 = w2h + (size_t)(ob + la) * CCH;
        const _Float16* arow1 = w2h + (size_t)(ob + 16 + la) * CCH;
        const _Float16* brow  = xT  + (size_t)(jb + la) * CCH;
        #pragma unroll
        for (int kk = 0; kk < CCH; kk += 32) {
            const half8 a0 = *(const half8*)(arow0 + kk + lg * 8);
            const half8 a1 = *(const half8*)(arow1 + kk + lg * 8);
            const half8 b  = *(const half8*)(brow  + kk + lg * 8);
            acc0 = __builtin_amdgcn_mfma_f32_16x16x32_f16(a0, b, acc0, 0, 0, 0);
            acc1 = __builtin_amdgcn_mfma_f32_16x16x32_f16(a1, b, acc1, 0, 0, 0);
        }
        const int h = (ob & 255) >> 5;
        const float4 b40 = *(const float4*)(b2 + ob + lg * 4);
        const float4 b41 = *(const float4*)(b2 + ob + 16 + lg * 4);
        const float bb0[4] = {b40.x, b40.y, b40.z, b40.w};
        const float bb1[4] = {b41.x, b41.y, b41.z, b41.w};
        #pragma unroll
        for (int r = 0; r < 4; ++r) {
            const int d0 = lg * 4 + r;
            vT_h[((size_t)h * DIM_HEAD + d0     ) * NTOK + jb + la] = (_Float16)(acc0[r] + bb0[r]);
            vT_h[((size_t)h * DIM_HEAD + d0 + 16) * NTOK + jb + la] = (_Float16)(acc1[r] + bb1[r]);
        }
    }
}

// -------------------- 4. Flash attention: 32x32 MFMA, P in registers, TJ=128 ---
#define TJ 128
#define KPAD 36
#define VPAD 136
__global__ __launch_bounds__(512)
void attn_mfma(const _Float16* __restrict__ q_h, const _Float16* __restrict__ k_h,
               const _Float16* __restrict__ vT_h,
               float* __restrict__ pm, float* __restrict__ pl,
               _Float16* __restrict__ pacc) {
    const int tid = threadIdx.x;                 // 0..511
    const int w = tid >> 6, lane = tid & 63;
    const int la32 = lane & 31, hi = lane >> 5;
    const int h = blockIdx.y;
    const int s = blockIdx.z;
    const int qbase = blockIdx.x * 256 + w * 32;
    const int jlen = NTOK / JS;          // 1024
    const int j0 = s * jlen;

    __shared__ _Float16 lk [2][TJ * KPAD];           // 2 x 9 KB (128 key rows)
    __shared__ _Float16 lvt[2][DIM_HEAD * VPAD];     // 2 x 8.5 KB (32 d rows x 128 cols)

    // Q B-fragments: lane holds Q row q=la32, d = c16*16 + hi*8 .. +7
    const _Float16* qrow = q_h + ((size_t)h * NTOK + qbase + la32) * DIM_HEAD;
    const half8 bq0 = *(const half8*)(qrow + hi * 8);
    const half8 bq1 = *(const half8*)(qrow + 16 + hi * 8);

    f32x16 acc;
    #pragma unroll
    for (int r = 0; r < 16; ++r) acc[r] = 0.f;
    float m = -1e30f, l = 0.f;           // per-lane: query la32 (replicated in hi)

    const _Float16* kg_ = k_h  + (size_t)h * NTOK * DIM_HEAD + (size_t)j0 * DIM_HEAD;
    const _Float16* vg  = vT_h + (size_t)h * DIM_HEAD * NTOK + j0;
    const int krow = tid >> 3, kc8 = tid & 7;       // K staging rows (x2: +64)
    const int vrow = tid >> 4, vseg = tid & 15;     // V^T staging (x2 col halves)

    uint2 k0r, k1r, v0r, v1r;
    // tile 0 -> buf0
    k0r = ((const uint2*)kg_)[tid];
    k1r = ((const uint2*)kg_)[tid + 512];
    v0r = *(const uint2*)(vg + (size_t)vrow * NTOK + vseg * 4);
    v1r = *(const uint2*)(vg + (size_t)vrow * NTOK + 64 + vseg * 4);
    *(uint2*)&lk[0][krow * KPAD + kc8 * 4]        = k0r;
    *(uint2*)&lk[0][(krow + 64) * KPAD + kc8 * 4] = k1r;
    *(uint2*)&lvt[0][vrow * VPAD + vseg * 4]      = v0r;
    *(uint2*)&lvt[0][vrow * VPAD + 64 + vseg * 4] = v1r;
    // tile 1 -> regs
    k0r = ((const uint2*)(kg_ + (size_t)TJ * DIM_HEAD))[tid];
    k1r = ((const uint2*)(kg_ + (size_t)TJ * DIM_HEAD))[tid + 512];
    v0r = *(const uint2*)(vg + (size_t)vrow * NTOK + TJ + vseg * 4);
    v1r = *(const uint2*)(vg + (size_t)vrow * NTOK + TJ + 64 + vseg * 4);
    __syncthreads();

    const int NT = jlen / TJ;     // 8
    for (int t = 0; t < NT; ++t) {
        const int cur = t & 1;
        if (t + 1 < NT) {
            *(uint2*)&lk[cur ^ 1][krow * KPAD + kc8 * 4]        = k0r;
            *(uint2*)&lk[cur ^ 1][(krow + 64) * KPAD + kc8 * 4] = k1r;
            *(uint2*)&lvt[cur ^ 1][vrow * VPAD + vseg * 4]      = v0r;
            *(uint2*)&lvt[cur ^ 1][vrow * VPAD + 64 + vseg * 4] = v1r;
            if (t + 2 < NT) {
                const _Float16* kt = kg_ + (size_t)(t + 2) * TJ * DIM_HEAD;
                k0r = ((const uint2*)kt)[tid];
                k1r = ((const uint2*)kt)[tid + 512];
                v0r = *(const uint2*)(vg + (size_t)vrow * NTOK + (t + 2) * TJ + vseg * 4);
                v1r = *(const uint2*)(vg + (size_t)vrow * NTOK + (t + 2) * TJ + 64 + vseg * 4);
            }
        }
        // ---- QK^T swapped (32x32), 4 key groups of 32 ----
        f32x16 z;
        #pragma unroll
        for (int r = 0; r < 16; ++r) z[r] = 0.f;
        #define QK_GROUP(SC, G)                                                        \
        f32x16 SC;                                                                     \
        {                                                                              \
            const half8 a0 = *(const half8*)&lk[cur][(32*(G) + la32) * KPAD +      hi * 8]; \
            const half8 a1 = *(const half8*)&lk[cur][(32*(G) + la32) * KPAD + 16 + hi * 8]; \
            SC = __builtin_amdgcn_mfma_f32_32x32x16_f16(a0, bq0, z, 0, 0, 0);          \
            SC = __builtin_amdgcn_mfma_f32_32x32x16_f16(a1, bq1, SC, 0, 0, 0);         \
        }
        QK_GROUP(sc0, 0)
        QK_GROUP(sc1, 1)
        QK_GROUP(sc2, 2)
        QK_GROUP(sc3, 3)
        #undef QK_GROUP
        // ---- linear max over 64 in-lane regs + 1 cross-replica shfl ----
        float tm = sc0[0];
        #pragma unroll
        for (int r = 1; r < 16; ++r) tm = fmaxf(tm, sc0[r]);
        #pragma unroll
        for (int r = 0; r < 16; ++r) tm = fmaxf(tm, sc1[r]);
        #pragma unroll
        for (int r = 0; r < 16; ++r) tm = fmaxf(tm, sc2[r]);
        #pragma unroll
        for (int r = 0; r < 16; ++r) tm = fmaxf(tm, sc3[r]);
        tm = fmaxf(tm, __shfl_xor(tm, 32));
        const float mn   = fmaxf(m, tm);
        const float corr = __expf(m - mn);
        m = mn;
        l *= corr;
        #pragma unroll
        for (int r = 0; r < 16; ++r) acc[r] *= corr;
        float ps = 0.f;
        // ---- per group: exps (registers) then 2 PV chunks ----
        #define DO_CHUNK(P, C2, CIDX)                                              \
        {                                                                          \
            union { fp16x2 hh; unsigned u; } A_, B_, C_, D_;                       \
            A_.hh = __builtin_amdgcn_cvt_pkrtz(P[8*(C2)+0], P[8*(C2)+1]);          \
            B_.hh = __builtin_amdgcn_cvt_pkrtz(P[8*(C2)+2], P[8*(C2)+3]);          \
            C_.hh = __builtin_amdgcn_cvt_pkrtz(P[8*(C2)+4], P[8*(C2)+5]);          \
            D_.hh = __builtin_amdgcn_cvt_pkrtz(P[8*(C2)+6], P[8*(C2)+7]);          \
            asm("v_permlane32_swap_b32 %0, %1" : "+v"(A_.u), "+v"(C_.u));          \
            asm("v_permlane32_swap_b32 %0, %1" : "+v"(B_.u), "+v"(D_.u));          \
            union { unsigned u[4]; half8 v; } F_;                                  \
            F_.u[0] = A_.u; F_.u[1] = B_.u; F_.u[2] = C_.u; F_.u[3] = D_.u;        \
            const half8 av = *(const half8*)&lvt[cur][la32 * VPAD + (CIDX) * 16 + hi * 8]; \
            acc = __builtin_amdgcn_mfma_f32_32x32x16_f16(av, F_.v, acc, 0, 0, 0);  \
        }
        #define PV_GROUP(SC, G)                                                    \
        {                                                                          \
            float p[16];                                                           \
            _Pragma("unroll")                                                      \
            for (int r = 0; r < 16; ++r) { p[r] = __expf(SC[r] - mn); ps += p[r]; } \
            DO_CHUNK(p, 0, 2*(G))                                                  \
            DO_CHUNK(p, 1, 2*(G)+1)                                                \
        }
        PV_GROUP(sc0, 0)
        PV_GROUP(sc1, 1)
        PV_GROUP(sc2, 2)
        PV_GROUP(sc3, 3)
        #undef PV_GROUP
        #undef DO_CHUNK
        l += ps;
        __syncthreads();
    }
    // ---- epilogue: combine replicas' l; store partial state ----
    float lt = l + __shfl_xor(l, 32);
    const size_t pbase = (size_t)(h * JS + s) * NTOK + qbase;
    if (hi == 0) {
        pm[pbase + la32] = m;
        pl[pbase + la32] = lt;
    }
    // acc[reg] holds out[d = (reg&3)+8*(reg>>2)+4*hi][q = la32]
    #pragma unroll
    for (int g = 0; g < 4; ++g) {
        union { fp16x2 hh; unsigned u; } u0, u1;
        u0.hh = __builtin_amdgcn_cvt_pkrtz(acc[4*g],     acc[4*g + 1]);
        u1.hh = __builtin_amdgcn_cvt_pkrtz(acc[4*g + 2], acc[4*g + 3]);
        uint2 st; st.x = u0.u; st.y = u1.u;
        *(uint2*)(pacc + (pbase + la32) * DIM_HEAD + 8 * g + 4 * hi) = st;
    }
}

// -------------------- 5. Output projection + FUSED split-K combine -------------
// Each kk-block of 32 channels is exactly one head h=kk>>5; the B-fragment for
// token j=jb+la is the combined attention output: per (j,h) compute the 4 split
// weights from pm/pl (L1-broadcast across lg), then weight-sum the 4 pacc half8s
// in f32 (same order as the old combine kernel) and convert. Removes the
// attn_combine launch and the attT round-trip.
__global__ __launch_bounds__(256)
void out_mfma(const _Float16* __restrict__ wouth, const float* __restrict__ bo,
              const float* __restrict__ pm, const float* __restrict__ pl,
              const _Float16* __restrict__ pacc, const float* __restrict__ x,
              float* __restrict__ out) {
    const int tid = threadIdx.x, w = tid >> 6, lane = tid & 63;
    const int la = lane & 15, lg = lane >> 4;
    const int jb = blockIdx.x * 64 + w * 16;
    const int ob = blockIdx.y * 32;
    const int j  = jb + la;                    // this lane's B token
    const _Float16* arow0 = wouth + (size_t)(ob + la) * CCH;        // D row = o
    const _Float16* arow1 = wouth + (size_t)(ob + 16 + la) * CCH;
    f32x4 acc0 = {0.f, 0.f, 0.f, 0.f};
    f32x4 acc1 = {0.f, 0.f, 0.f, 0.f};
    #pragma unroll
    for (int kk = 0; kk < CCH; kk += 32) {
        const int hh = kk >> 5;                // head for this channel block
        // ---- combine weights for (token j, head hh) ----
        float mv[JS], lv[JS];
        #pragma unroll
        for (int s2 = 0; s2 < JS; ++s2) {
            const size_t pidx = ((size_t)(hh * JS + s2) * NTOK + j);
            mv[s2] = pm[pidx];
            lv[s2] = pl[pidx];
        }
        const float mM = fmaxf(fmaxf(mv[0], mv[1]), fmaxf(mv[2], mv[3]));
        float wv[JS], denom = 0.f;
        #pragma unroll
        for (int s2 = 0; s2 < JS; ++s2) {
            wv[s2] = __expf(mv[s2] - mM);
            denom += lv[s2] * wv[s2];
        }
        const float inv = 1.f / denom;
        // ---- combined B fragment: dims lg*8..+7 of head hh ----
        float bd[8] = {0.f, 0.f, 0.f, 0.f, 0.f, 0.f, 0.f, 0.f};
        #pragma unroll
        for (int s2 = 0; s2 < JS; ++s2) {
            const half8 pa = *(const half8*)(pacc
                + (((size_t)(hh * JS + s2) * NTOK + j) << 5) + lg * 8);
            #pragma unroll
            for (int e = 0; e < 8; ++e) bd[e] += wv[s2] * (float)pa[e];
        }
        union { _Float16 hsrc[8]; half8 v; } bb_;
        #pragma unroll
        for (int e = 0; e < 8; ++e) bb_.hsrc[e] = (_Float16)(bd[e] * inv);
        // ---- GEMM step ----
        const half8 a0 = *(const half8*)(arow0 + kk + lg * 8);
        const half8 a1 = *(const half8*)(arow1 + kk + lg * 8);
        acc0 = __builtin_amdgcn_mfma_f32_16x16x32_f16(a0, bb_.v, acc0, 0, 0, 0);
        acc1 = __builtin_amdgcn_mfma_f32_16x16x32_f16(a1, bb_.v, acc1, 0, 0, 0);
    }
    const float4 b40 = *(const float4*)(bo + ob + lg * 4);
    const float4 b41 = *(const float4*)(bo + ob + 16 + lg * 4);
    const float bb0[4] = {b40.x, b40.y, b40.z, b40.w};
    const float bb1[4] = {b41.x, b41.y, b41.z, b41.w};
    #pragma unroll
    for (int r = 0; r < 4; ++r) {
        const int o0 = ob + lg * 4 + r;
        const size_t idx0 = (size_t)o0 * NTOK + jb + la;
        out[idx0] = acc0[r] + bb0[r] + x[idx0];
        const int o1 = ob + 16 + lg * 4 + r;
        const size_t idx1 = (size_t)o1 * NTOK + jb + la;
        out[idx1] = acc1[r] + bb1[r] + x[idx1];
    }
}

extern "C" void kernel_launch(void* const* d_in, const int* in_sizes, int n_in,
                              void* d_out, int out_size, void* d_ws, size_t ws_size,
                              hipStream_t stream) {
    const float* x     = (const float*)d_in[0];
    const float* gamma = (const float*)d_in[1];
    const float* beta  = (const float*)d_in[2];
    const float* w_qkv = (const float*)d_in[3];
    const float* b_qkv = (const float*)d_in[4];
    const float* w_out = (const float*)d_in[5];
    const float* b_out = (const float*)d_in[6];
    float* out = (float*)d_out;

    float* ws   = (float*)d_ws;
    float* part = ws;                           // 512
    float* b2   = part + 512;                   // 768
    float* pm   = b2 + 768;                     // 8*4*4096 = 131072
    float* pl   = pm + 131072;                  // 131072
    _Float16* pacc = (_Float16*)(pl + 131072);  // 8*4*4096*32 halves (8.4 MB)
    float* fend = pl + 131072 + 2097152;        // pacc = 2097152 floats worth
    _Float16* q_h   = (_Float16*)fend;          // 1048576 halves each
    _Float16* k_h   = q_h  + 1048576;
    _Float16* vT_h  = k_h  + 1048576;
    _Float16* xT    = vT_h + 1048576;           // 1048576
    _Float16* w2h   = xT   + 1048576;           // 196608
    _Float16* wouth = w2h  + 196608;            // 65536
    // total ~21 MB (ws proven >= 92 MB in round 2)

    {
        dim3 g(GN_SPLIT, GROUPS);
        gn_stats_partial<<<g, 256, 0, stream>>>(x, part);
    }
    fold_qkv<<<5 * CCH, 256, 0, stream>>>(w_qkv, b_qkv, gamma, beta, part, w_out, x,
                                          w2h, b2, wouth, xT);
    {
        dim3 g(NTOK / 64, 3 * CCH / 32);
        qkv_mfma<<<g, 256, 0, stream>>>(w2h, b2, xT, q_h, k_h, vT_h);
    }
    {
        dim3 g(NTOK / 256, HEADS, JS);
        attn_mfma<<<g, 512, 0, stream>>>(q_h, k_h, vT_h, pm, pl, pacc);
    }
    {
        dim3 g(NTOK / 64, CCH / 32);
        out_mfma<<<g, 256, 0, stream>>>(wouth, b_out, pm, pl, pacc, x, out);
    }
}

// Round 25
// 77.876 us; speedup vs baseline: 1.0270x; 1.0270x over previous
//
#include <hip/hip_runtime.h>
#include <hip/hip_bf16.h>

#define HEADS 8
#define DIM_HEAD 32
#define GROUPS 8
#define CCH 256            // channels
#define NTOK 4096          // d*h*w = 16^3
#define EPS 1e-5f
#define GN_SPLIT 32
#define JS 4               // attention j-split

typedef _Float16 half8 __attribute__((ext_vector_type(8)));
typedef _Float16 half4 __attribute__((ext_vector_type(4)));
typedef __fp16   fp16x2 __attribute__((ext_vector_type(2)));   // cvt_pkrtz return type
typedef float f32x4 __attribute__((ext_vector_type(4)));
typedef float f32x16 __attribute__((ext_vector_type(16)));

// -------------------- 1. GroupNorm partial stats --------------------
__global__ void gn_stats_partial(const float* __restrict__ x, float* __restrict__ part) {
    const int g  = blockIdx.y;
    const int sp = blockIdx.x;
    const int M = (CCH / GROUPS) * NTOK;        // 131072 contiguous floats per group
    const int chunk = M / GN_SPLIT;             // 4096
    const float4* p = (const float4*)(x + (size_t)g * M + (size_t)sp * chunk);
    float s = 0.f, ss = 0.f;
    for (int i = threadIdx.x; i < chunk / 4; i += blockDim.x) {
        float4 v = p[i];
        s  += v.x + v.y + v.z + v.w;
        ss += v.x*v.x + v.y*v.y + v.z*v.z + v.w*v.w;
    }
    #pragma unroll
    for (int off = 32; off; off >>= 1) {
        s  += __shfl_down(s,  off);
        ss += __shfl_down(ss, off);
    }
    __shared__ float sh0[8], sh1[8];
    const int wave = threadIdx.x >> 6, lane = threadIdx.x & 63;
    if (lane == 0) { sh0[wave] = s; sh1[wave] = ss; }
    __syncthreads();
    if (threadIdx.x == 0) {
        float S = 0.f, SS = 0.f;
        const int nw = blockDim.x >> 6;
        for (int w = 0; w < nw; ++w) { S += sh0[w]; SS += sh1[w]; }
        part[(g * GN_SPLIT + sp) * 2]     = S;
        part[(g * GN_SPLIT + sp) * 2 + 1] = SS;
    }
}

// -------------------- 2. Fold GN into QKV weights + w_out fp16 + x transpose ----
__global__ __launch_bounds__(256)
void fold_qkv(const float* __restrict__ w, const float* __restrict__ b,
              const float* __restrict__ gamma, const float* __restrict__ beta,
              const float* __restrict__ part, const float* __restrict__ w_out,
              const float* __restrict__ x,
              _Float16* __restrict__ w2h, float* __restrict__ b2,
              _Float16* __restrict__ wouth, _Float16* __restrict__ xT) {
    const int o = blockIdx.x;
    const int c = threadIdx.x;          // 0..255
    if (o >= 4 * CCH) {                 // ---- transpose tile ----
        const int t  = o - 4 * CCH;     // 0..255
        const int jb = (t & 63) * 64;
        const int cb = (t >> 6) * 64;
        __shared__ float tile[64][65];
        const int tj = threadIdx.x & 63, tc = threadIdx.x >> 6;
        #pragma unroll
        for (int cc = 0; cc < 64; cc += 4)
            tile[cc + tc][tj] = x[(size_t)(cb + cc + tc) * NTOK + jb + tj];
        __syncthreads();
        const int wc = threadIdx.x & 63, wj = threadIdx.x >> 6;
        #pragma unroll
        for (int jj = 0; jj < 64; jj += 4)
            xT[(size_t)(jb + jj + wj) * CCH + cb + wc] = (_Float16)tile[wc][jj + wj];
        return;
    }
    if (o >= 3 * CCH) {                 // ---- w_out convert ----
        const int oo = o - 3 * CCH;
        wouth[(size_t)oo * CCH + c] = (_Float16)w_out[(size_t)oo * CCH + c];
        return;
    }
    __shared__ float smean[GROUPS], srstd[GROUPS];
    if (c < GROUPS) {
        float s = 0.f, ss = 0.f;
        #pragma unroll
        for (int i = 0; i < GN_SPLIT; ++i) {
            s  += part[(c * GN_SPLIT + i) * 2];
            ss += part[(c * GN_SPLIT + i) * 2 + 1];
        }
        const float M = (float)((CCH / GROUPS) * NTOK);
        const float mean = s / M;
        const float var  = ss / M - mean * mean;
        smean[c] = mean;
        srstd[c] = rsqrtf(var + EPS);
    }
    __syncthreads();
    const int g = c >> 5;
    const float sc = gamma[c] * srstd[g];
    const float sh = beta[c] - smean[g] * sc;
    const float wv = w[(size_t)o * CCH + c];
    w2h[(size_t)o * CCH + c] = (_Float16)(wv * sc);
    float t = wv * sh;
    #pragma unroll
    for (int off = 32; off; off >>= 1) t += __shfl_down(t, off);
    __shared__ float shred[4];
    const int wave = threadIdx.x >> 6, lane = threadIdx.x & 63;
    if (lane == 0) shred[wave] = t;
    __syncthreads();
    if (threadIdx.x == 0)
        b2[o] = b[o] + shred[0] + shred[1] + shred[2] + shred[3];
}

// -------------------- 3. QKV GEMM via MFMA, 32 outputs/wave --------------------
__global__ __launch_bounds__(256)
void qkv_mfma(const _Float16* __restrict__ w2h, const float* __restrict__ b2,
              const _Float16* __restrict__ xT,
              _Float16* __restrict__ q_h, _Float16* __restrict__ k_h,
              _Float16* __restrict__ vT_h) {
    const int tid = threadIdx.x, w = tid >> 6, lane = tid & 63;
    const int la = lane & 15, lg = lane >> 4;
    const int jb = blockIdx.x * 64 + w * 16;   // wave's 16 tokens
    const int ob = blockIdx.y * 32;            // 32 output rows (32-aligned: same part/h)
    const int part = ob >> 8;
    f32x4 acc0 = {0.f, 0.f, 0.f, 0.f};
    f32x4 acc1 = {0.f, 0.f, 0.f, 0.f};
    if (part < 2) {
        // A = xT token rows (D row = j), B = w2h o-rows (D col = o)
        const _Float16* arow  = xT  + (size_t)(jb + la) * CCH;
        const _Float16* brow0 = w2h + (size_t)(ob + la) * CCH;
        const _Float16* brow1 = w2h + (size_t)(ob + 16 + la) * CCH;
        #pragma unroll
        for (int kk = 0; kk < CCH; kk += 32) {
            const half8 a  = *(const half8*)(arow  + kk + lg * 8);
            const half8 b0 = *(const half8*)(brow0 + kk + lg * 8);
            const half8 b1 = *(const half8*)(brow1 + kk + lg * 8);
            acc0 = __builtin_amdgcn_mfma_f32_16x16x32_f16(a, b0, acc0, 0, 0, 0);
            acc1 = __builtin_amdgcn_mfma_f32_16x16x32_f16(a, b1, acc1, 0, 0, 0);
        }
        const int h = (ob & 255) >> 5;
        const float bias0 = b2[ob + la];
        const float bias1 = b2[ob + 16 + la];
        _Float16* dst = (part == 0) ? q_h : k_h;
        const float scl = (part == 0) ? 0.17677669529663687f : 1.0f;  // 32^-0.5
        #pragma unroll
        for (int r = 0; r < 4; ++r) {
            const int j = jb + lg * 4 + r;
            _Float16* base = dst + ((size_t)h * NTOK + j) * DIM_HEAD;
            base[la]      = (_Float16)((acc0[r] + bias0) * scl);
            base[16 + la] = (_Float16)((acc1[r] + bias1) * scl);
        }
    } else {
        // A = w2h o-rows (D row = o=d), B = xT token rows (D col = j)
        const _Float16* arow0 = w2h + (size_t)(ob + la) * CCH;
        const _Float16* arow1 = w2h + (size_t)(ob + 16 + la) * CCH;
        const _Float16* brow  = xT  + (size_t)(jb + la) * CCH;
        #pragma unroll
        for (int kk = 0; kk < CCH; kk += 32) {
            const half8 a0 = *(const half8*)(arow0 + kk + lg * 8);
            const half8 a1 = *(const half8*)(arow1 + kk + lg * 8);
            const half8 b  = *(const half8*)(brow  + kk + lg * 8);
            acc0 = __builtin_amdgcn_mfma_f32_16x16x32_f16(a0, b, acc0, 0, 0, 0);
            acc1 = __builtin_amdgcn_mfma_f32_16x16x32_f16(a1, b, acc1, 0, 0, 0);
        }
        const int h = (ob & 255) >> 5;
        const float4 b40 = *(const float4*)(b2 + ob + lg * 4);
        const float4 b41 = *(const float4*)(b2 + ob + 16 + lg * 4);
        const float bb0[4] = {b40.x, b40.y, b40.z, b40.w};
        const float bb1[4] = {b41.x, b41.y, b41.z, b41.w};
        #pragma unroll
        for (int r = 0; r < 4; ++r) {
            const int d0 = lg * 4 + r;
            vT_h[((size_t)h * DIM_HEAD + d0     ) * NTOK + jb + la] = (_Float16)(acc0[r] + bb0[r]);
            vT_h[((size_t)h * DIM_HEAD + d0 + 16) * NTOK + jb + la] = (_Float16)(acc1[r] + bb1[r]);
        }
    }
}

// -------------------- 4. Flash attention: 32x32 MFMA, P in registers, TJ=128 ---
#define TJ 128
#define KPAD 36
#define VPAD 136
__global__ __launch_bounds__(512)
void attn_mfma(const _Float16* __restrict__ q_h, const _Float16* __restrict__ k_h,
               const _Float16* __restrict__ vT_h,
               float* __restrict__ pm, float* __restrict__ pl,
               _Float16* __restrict__ pacc) {
    const int tid = threadIdx.x;                 // 0..511
    const int w = tid >> 6, lane = tid & 63;
    const int la32 = lane & 31, hi = lane >> 5;
    const int h = blockIdx.y;
    const int s = blockIdx.z;
    const int qbase = blockIdx.x * 256 + w * 32;
    const int jlen = NTOK / JS;          // 1024
    const int j0 = s * jlen;

    __shared__ _Float16 lk [2][TJ * KPAD];           // 2 x 9 KB (128 key rows)
    __shared__ _Float16 lvt[2][DIM_HEAD * VPAD];     // 2 x 8.5 KB (32 d rows x 128 cols)

    // Q B-fragments: lane holds Q row q=la32, d = c16*16 + hi*8 .. +7
    const _Float16* qrow = q_h + ((size_t)h * NTOK + qbase + la32) * DIM_HEAD;
    const half8 bq0 = *(const half8*)(qrow + hi * 8);
    const half8 bq1 = *(const half8*)(qrow + 16 + hi * 8);

    f32x16 acc;
    #pragma unroll
    for (int r = 0; r < 16; ++r) acc[r] = 0.f;
    float m = -1e30f, l = 0.f;           // per-lane: query la32 (replicated in hi)

    const _Float16* kg_ = k_h  + (size_t)h * NTOK * DIM_HEAD + (size_t)j0 * DIM_HEAD;
    const _Float16* vg  = vT_h + (size_t)h * DIM_HEAD * NTOK + j0;
    const int krow = tid >> 3, kc8 = tid & 7;       // K staging rows (x2: +64)
    const int vrow = tid >> 4, vseg = tid & 15;     // V^T staging (x2 col halves)

    uint2 k0r, k1r, v0r, v1r;
    // tile 0 -> buf0
    k0r = ((const uint2*)kg_)[tid];
    k1r = ((const uint2*)kg_)[tid + 512];
    v0r = *(const uint2*)(vg + (size_t)vrow * NTOK + vseg * 4);
    v1r = *(const uint2*)(vg + (size_t)vrow * NTOK + 64 + vseg * 4);
    *(uint2*)&lk[0][krow * KPAD + kc8 * 4]        = k0r;
    *(uint2*)&lk[0][(krow + 64) * KPAD + kc8 * 4] = k1r;
    *(uint2*)&lvt[0][vrow * VPAD + vseg * 4]      = v0r;
    *(uint2*)&lvt[0][vrow * VPAD + 64 + vseg * 4] = v1r;
    // tile 1 -> regs
    k0r = ((const uint2*)(kg_ + (size_t)TJ * DIM_HEAD))[tid];
    k1r = ((const uint2*)(kg_ + (size_t)TJ * DIM_HEAD))[tid + 512];
    v0r = *(const uint2*)(vg + (size_t)vrow * NTOK + TJ + vseg * 4);
    v1r = *(const uint2*)(vg + (size_t)vrow * NTOK + TJ + 64 + vseg * 4);
    __syncthreads();

    const int NT = jlen / TJ;     // 8
    for (int t = 0; t < NT; ++t) {
        const int cur = t & 1;
        if (t + 1 < NT) {
            *(uint2*)&lk[cur ^ 1][krow * KPAD + kc8 * 4]        = k0r;
            *(uint2*)&lk[cur ^ 1][(krow + 64) * KPAD + kc8 * 4] = k1r;
            *(uint2*)&lvt[cur ^ 1][vrow * VPAD + vseg * 4]      = v0r;
            *(uint2*)&lvt[cur ^ 1][vrow * VPAD + 64 + vseg * 4] = v1r;
            if (t + 2 < NT) {
                const _Float16* kt = kg_ + (size_t)(t + 2) * TJ * DIM_HEAD;
                k0r = ((const uint2*)kt)[tid];
                k1r = ((const uint2*)kt)[tid + 512];
                v0r = *(const uint2*)(vg + (size_t)vrow * NTOK + (t + 2) * TJ + vseg * 4);
                v1r = *(const uint2*)(vg + (size_t)vrow * NTOK + (t + 2) * TJ + 64 + vseg * 4);
            }
        }
        // ---- QK^T swapped (32x32), 4 key groups of 32 ----
        f32x16 z;
        #pragma unroll
        for (int r = 0; r < 16; ++r) z[r] = 0.f;
        #define QK_GROUP(SC, G)                                                        \
        f32x16 SC;                                                                     \
        {                                                                              \
            const half8 a0 = *(const half8*)&lk[cur][(32*(G) + la32) * KPAD +      hi * 8]; \
            const half8 a1 = *(const half8*)&lk[cur][(32*(G) + la32) * KPAD + 16 + hi * 8]; \
            SC = __builtin_amdgcn_mfma_f32_32x32x16_f16(a0, bq0, z, 0, 0, 0);          \
            SC = __builtin_amdgcn_mfma_f32_32x32x16_f16(a1, bq1, SC, 0, 0, 0);         \
        }
        QK_GROUP(sc0, 0)
        QK_GROUP(sc1, 1)
        QK_GROUP(sc2, 2)
        QK_GROUP(sc3, 3)
        #undef QK_GROUP
        // ---- linear max over 64 in-lane regs + 1 cross-replica shfl ----
        float tm = sc0[0];
        #pragma unroll
        for (int r = 1; r < 16; ++r) tm = fmaxf(tm, sc0[r]);
        #pragma unroll
        for (int r = 0; r < 16; ++r) tm = fmaxf(tm, sc1[r]);
        #pragma unroll
        for (int r = 0; r < 16; ++r) tm = fmaxf(tm, sc2[r]);
        #pragma unroll
        for (int r = 0; r < 16; ++r) tm = fmaxf(tm, sc3[r]);
        tm = fmaxf(tm, __shfl_xor(tm, 32));
        const float mn   = fmaxf(m, tm);
        const float corr = __expf(m - mn);
        m = mn;
        l *= corr;
        #pragma unroll
        for (int r = 0; r < 16; ++r) acc[r] *= corr;
        float ps = 0.f;
        // ---- per group: exps (registers) then 2 PV chunks ----
        #define DO_CHUNK(P, C2, CIDX)                                              \
        {                                                                          \
            union { fp16x2 hh; unsigned u; } A_, B_, C_, D_;                       \
            A_.hh = __builtin_amdgcn_cvt_pkrtz(P[8*(C2)+0], P[8*(C2)+1]);          \
            B_.hh = __builtin_amdgcn_cvt_pkrtz(P[8*(C2)+2], P[8*(C2)+3]);          \
            C_.hh = __builtin_amdgcn_cvt_pkrtz(P[8*(C2)+4], P[8*(C2)+5]);          \
            D_.hh = __builtin_amdgcn_cvt_pkrtz(P[8*(C2)+6], P[8*(C2)+7]);          \
            asm("v_permlane32_swap_b32 %0, %1" : "+v"(A_.u), "+v"(C_.u));          \
            asm("v_permlane32_swap_b32 %0, %1" : "+v"(B_.u), "+v"(D_.u));          \
            union { unsigned u[4]; half8 v; } F_;                                  \
            F_.u[0] = A_.u; F_.u[1] = B_.u; F_.u[2] = C_.u; F_.u[3] = D_.u;        \
            const half8 av = *(const half8*)&lvt[cur][la32 * VPAD + (CIDX) * 16 + hi * 8]; \
            acc = __builtin_amdgcn_mfma_f32_32x32x16_f16(av, F_.v, acc, 0, 0, 0);  \
        }
        #define PV_GROUP(SC, G)                                                    \
        {                                                                          \
            float p[16];                                                           \
            _Pragma("unroll")                                                      \
            for (int r = 0; r < 16; ++r) { p[r] = __expf(SC[r] - mn); ps += p[r]; } \
            DO_CHUNK(p, 0, 2*(G))                                                  \
            DO_CHUNK(p, 1, 2*(G)+1)                                                \
        }
        PV_GROUP(sc0, 0)
        PV_GROUP(sc1, 1)
        PV_GROUP(sc2, 2)
        PV_GROUP(sc3, 3)
        #undef PV_GROUP
        #undef DO_CHUNK
        l += ps;
        __syncthreads();
    }
    // ---- epilogue: combine replicas' l; store partial state ----
    float lt = l + __shfl_xor(l, 32);
    const size_t pbase = (size_t)(h * JS + s) * NTOK + qbase;
    if (hi == 0) {
        pm[pbase + la32] = m;
        pl[pbase + la32] = lt;
    }
    // acc[reg] holds out[d = (reg&3)+8*(reg>>2)+4*hi][q = la32]
    #pragma unroll
    for (int g = 0; g < 4; ++g) {
        union { fp16x2 hh; unsigned u; } u0, u1;
        u0.hh = __builtin_amdgcn_cvt_pkrtz(acc[4*g],     acc[4*g + 1]);
        u1.hh = __builtin_amdgcn_cvt_pkrtz(acc[4*g + 2], acc[4*g + 3]);
        uint2 st; st.x = u0.u; st.y = u1.u;
        *(uint2*)(pacc + (pbase + la32) * DIM_HEAD + 8 * g + 4 * hi) = st;
    }
}

// -------------------- 5. Combine partials (JS=4, fp16 pacc) -> attT fp16 -------
__global__ void attn_combine(const float* __restrict__ pm, const float* __restrict__ pl,
                             const _Float16* __restrict__ pacc, _Float16* __restrict__ attT) {
    const int i = blockIdx.x * blockDim.x + threadIdx.x;   // 0..4095
    const int h = blockIdx.y;
    float mv[JS], lv[JS];
    float mM = -1e30f;
    #pragma unroll
    for (int s = 0; s < JS; ++s) {
        const size_t pidx = ((size_t)(h * JS + s) * NTOK + i);
        mv[s] = pm[pidx];
        lv[s] = pl[pidx];
        mM = fmaxf(mM, mv[s]);
    }
    float wv[JS];
    float denom = 0.f;
    #pragma unroll
    for (int s = 0; s < JS; ++s) {
        wv[s] = __expf(mv[s] - mM);
        denom += lv[s] * wv[s];
    }
    const float inv = 1.f / denom;
    __attribute__((aligned(16))) _Float16 hv[DIM_HEAD];
    #pragma unroll
    for (int d0 = 0; d0 < DIM_HEAD; d0 += 4) {
        float o0 = 0.f, o1 = 0.f, o2 = 0.f, o3 = 0.f;
        #pragma unroll
        for (int s = 0; s < JS; ++s) {
            const size_t pidx = ((size_t)(h * JS + s) * NTOK + i);
            const half4 a = *(const half4*)(pacc + pidx * DIM_HEAD + d0);
            o0 = fmaf((float)a.x, wv[s], o0);
            o1 = fmaf((float)a.y, wv[s], o1);
            o2 = fmaf((float)a.z, wv[s], o2);
            o3 = fmaf((float)a.w, wv[s], o3);
        }
        hv[d0]     = (_Float16)(o0 * inv);
        hv[d0 + 1] = (_Float16)(o1 * inv);
        hv[d0 + 2] = (_Float16)(o2 * inv);
        hv[d0 + 3] = (_Float16)(o3 * inv);
    }
    _Float16* dst = attT + (size_t)i * CCH + h * DIM_HEAD;   // 64 B contiguous
    #pragma unroll
    for (int q = 0; q < 4; ++q) ((uint4*)dst)[q] = ((const uint4*)hv)[q];
}

// -------------------- 6. Output projection via MFMA, 32 outputs/wave -----------
__global__ __launch_bounds__(256)
void out_mfma(const _Float16* __restrict__ wouth, const float* __restrict__ bo,
              const _Float16* __restrict__ attT, const float* __restrict__ x,
              float* __restrict__ out) {
    const int tid = threadIdx.x, w = tid >> 6, lane = tid & 63;
    const int la = lane & 15, lg = lane >> 4;
    const int jb = blockIdx.x * 64 + w * 16;
    const int ob = blockIdx.y * 32;
    const _Float16* arow0 = wouth + (size_t)(ob + la) * CCH;        // D row = o
    const _Float16* arow1 = wouth + (size_t)(ob + 16 + la) * CCH;
    const _Float16* brow  = attT  + (size_t)(jb + la) * CCH;        // D col = j
    f32x4 acc0 = {0.f, 0.f, 0.f, 0.f};
    f32x4 acc1 = {0.f, 0.f, 0.f, 0.f};
    #pragma unroll
    for (int kk = 0; kk < CCH; kk += 32) {
        const half8 a0 = *(const half8*)(arow0 + kk + lg * 8);
        const half8 a1 = *(const half8*)(arow1 + kk + lg * 8);
        const half8 b  = *(const half8*)(brow  + kk + lg * 8);
        acc0 = __builtin_amdgcn_mfma_f32_16x16x32_f16(a0, b, acc0, 0, 0, 0);
        acc1 = __builtin_amdgcn_mfma_f32_16x16x32_f16(a1, b, acc1, 0, 0, 0);
    }
    const float4 b40 = *(const float4*)(bo + ob + lg * 4);
    const float4 b41 = *(const float4*)(bo + ob + 16 + lg * 4);
    const float bb0[4] = {b40.x, b40.y, b40.z, b40.w};
    const float bb1[4] = {b41.x, b41.y, b41.z, b41.w};
    #pragma unroll
    for (int r = 0; r < 4; ++r) {
        const int o0 = ob + lg * 4 + r;
        const size_t idx0 = (size_t)o0 * NTOK + jb + la;
        out[idx0] = acc0[r] + bb0[r] + x[idx0];
        const int o1 = ob + 16 + lg * 4 + r;
        const size_t idx1 = (size_t)o1 * NTOK + jb + la;
        out[idx1] = acc1[r] + bb1[r] + x[idx1];
    }
}

extern "C" void kernel_launch(void* const* d_in, const int* in_sizes, int n_in,
                              void* d_out, int out_size, void* d_ws, size_t ws_size,
                              hipStream_t stream) {
    const float* x     = (const float*)d_in[0];
    const float* gamma = (const float*)d_in[1];
    const float* beta  = (const float*)d_in[2];
    const float* w_qkv = (const float*)d_in[3];
    const float* b_qkv = (const float*)d_in[4];
    const float* w_out = (const float*)d_in[5];
    const float* b_out = (const float*)d_in[6];
    float* out = (float*)d_out;

    float* ws   = (float*)d_ws;
    float* part = ws;                           // 512
    float* b2   = part + 512;                   // 768
    float* pm   = b2 + 768;                     // 8*4*4096 = 131072
    float* pl   = pm + 131072;                  // 131072
    _Float16* pacc = (_Float16*)(pl + 131072);  // 8*4*4096*32 halves (8.4 MB)
    float* fend = pl + 131072 + 2097152;        // pacc = 2097152 floats worth
    _Float16* q_h   = (_Float16*)fend;          // 1048576 halves each
    _Float16* k_h   = q_h  + 1048576;
    _Float16* vT_h  = k_h  + 1048576;
    _Float16* xT    = vT_h + 1048576;           // 1048576
    _Float16* w2h   = xT   + 1048576;           // 196608
    _Float16* wouth = w2h  + 196608;            // 65536
    _Float16* attT  = wouth + 65536;            // 1048576
    // total ~23 MB (ws proven >= 92 MB in round 2)

    {
        dim3 g(GN_SPLIT, GROUPS);
        gn_stats_partial<<<g, 256, 0, stream>>>(x, part);
    }
    fold_qkv<<<5 * CCH, 256, 0, stream>>>(w_qkv, b_qkv, gamma, beta, part, w_out, x,
                                          w2h, b2, wouth, xT);
    {
        dim3 g(NTOK / 64, 3 * CCH / 32);
        qkv_mfma<<<g, 256, 0, stream>>>(w2h, b2, xT, q_h, k_h, vT_h);
    }
    {
        dim3 g(NTOK / 256, HEADS, JS);
        attn_mfma<<<g, 512, 0, stream>>>(q_h, k_h, vT_h, pm, pl, pacc);
    }
    {
        dim3 g(NTOK / 256, HEADS);
        attn_combine<<<g, 256, 0, stream>>>(pm, pl, pacc, attT);
    }
    {
        dim3 g(NTOK / 64, CCH / 32);
        out_mfma<<<g, 256, 0, stream>>>(wouth, b_out, attT, x, out);
    }
}